// Round 1
// baseline (845.948 us; speedup 1.0000x reference)
//
#include <hip/hip_runtime.h>
#include <stdint.h>

#define NU 100000
#define NI 200000
#define NT 300000          // NU + NI
#define D 64
#define NNZ 1200000
#define NHOPS 3
#define SL 4               // slices per row = NHOPS+1
#define ROWF (SL * D)      // 256 floats per output row

__host__ __device__ __forceinline__ uint32_t rotl32(uint32_t x, int r) {
    return (x << r) | (x >> (32 - r));
}

// Threefry-2x32, 20 rounds — matches jax._src.prng.threefry2x32
__host__ __device__ inline void tf2x32(uint32_t k0, uint32_t k1,
                                       uint32_t x0, uint32_t x1,
                                       uint32_t& o0, uint32_t& o1) {
    uint32_t ks0 = k0, ks1 = k1, ks2 = k0 ^ k1 ^ 0x1BD11BDAu;
    x0 += ks0; x1 += ks1;
#define RND(r) { x0 += x1; x1 = rotl32(x1, r); x1 ^= x0; }
    RND(13) RND(15) RND(26) RND(6)
    x0 += ks1; x1 += ks2 + 1u;
    RND(17) RND(29) RND(16) RND(24)
    x0 += ks2; x1 += ks0 + 2u;
    RND(13) RND(15) RND(26) RND(6)
    x0 += ks0; x1 += ks1 + 3u;
    RND(17) RND(29) RND(16) RND(24)
    x0 += ks1; x1 += ks2 + 4u;
    RND(13) RND(15) RND(26) RND(6)
    o0 = x0 + ks2; o1 = x1 + ks0 + 5u;
#undef RND
}

// partitionable random_bits for flat index j: counter (0, j), bits = o0 ^ o1
__device__ __forceinline__ uint32_t rbits(uint32_t k0, uint32_t k1, uint32_t j) {
    uint32_t o0, o1;
    tf2x32(k0, k1, 0u, j, o0, o1);
    return o0 ^ o1;
}

__device__ __forceinline__ float u01(uint32_t bits) {
    return __uint_as_float((bits >> 9) | 0x3f800000u) - 1.0f;
}

// hop-0 copy (concat user/item) + zero slices 1..3.  One thread per float4.
__global__ void init_kernel(const float4* __restrict__ ue,
                            const float4* __restrict__ ie,
                            float4* __restrict__ out) {
    int gid = blockIdx.x * blockDim.x + threadIdx.x;   // over NT*16
    if (gid >= NT * 16) return;
    int n = gid >> 4, q = gid & 15;
    float4 v = (n < NU) ? ue[n * 16 + q] : ie[(n - NU) * 16 + q];
    float4 z = make_float4(0.f, 0.f, 0.f, 0.f);
    float4* row = out + (size_t)n * 64;                // 64 float4 per row
    row[q]      = v;
    row[16 + q] = z;
    row[32 + q] = z;
    row[48 + q] = z;
}

// edge dropout: v[e] = keep ? vals[e]*2 : 0   (keep iff u >= 0.5)
__global__ void edge_drop_kernel(const float* __restrict__ vals,
                                 float* __restrict__ v,
                                 uint32_t ke0, uint32_t ke1) {
    int e = blockIdx.x * blockDim.x + threadIdx.x;
    if (e >= NNZ) return;
    float u = u01(rbits(ke0, ke1, (uint32_t)e));
    v[e] = (u >= 0.5f) ? vals[e] * 2.0f : 0.0f;
}

// one wave (64 lanes) per edge; lane = feature dim
__global__ void spmm_kernel(const float* __restrict__ v,
                            const int* __restrict__ rows,
                            const int* __restrict__ cols,
                            float* __restrict__ out, int hop) {
    int wid  = (blockIdx.x * blockDim.x + threadIdx.x) >> 6;
    int lane = threadIdx.x & 63;
    if (wid >= NNZ) return;
    float ve = v[wid];
    if (ve == 0.0f) return;                      // dropped edge: exact no-op
    int r = rows[wid], c = cols[wid];
    float x = out[c * ROWF + hop * D + lane];
    unsafeAtomicAdd(&out[r * ROWF + (hop + 1) * D + lane], ve * x);
}

// fallback spmm with inline RNG (used only if ws too small)
__global__ void spmm_inline_kernel(const float* __restrict__ vals,
                                   const int* __restrict__ rows,
                                   const int* __restrict__ cols,
                                   float* __restrict__ out, int hop,
                                   uint32_t ke0, uint32_t ke1) {
    int wid  = (blockIdx.x * blockDim.x + threadIdx.x) >> 6;
    int lane = threadIdx.x & 63;
    if (wid >= NNZ) return;
    float u = u01(rbits(ke0, ke1, (uint32_t)wid));
    if (u < 0.5f) return;
    float ve = vals[wid] * 2.0f;
    int r = rows[wid], c = cols[wid];
    float x = out[c * ROWF + hop * D + lane];
    unsafeAtomicAdd(&out[r * ROWF + (hop + 1) * D + lane], ve * x);
}

// in-place inverted dropout on slice hop+1; flat index j over [NT, D]
__global__ void mess_drop_kernel(float* __restrict__ out, int hop,
                                 uint32_t km0, uint32_t km1) {
    int j = blockIdx.x * blockDim.x + threadIdx.x;
    if (j >= NT * D) return;
    float u = u01(rbits(km0, km1, (uint32_t)j));
    int n = j >> 6, d = j & 63;
    int idx = n * ROWF + (hop + 1) * D + d;
    const float P_KEEP = (float)(1.0 - 0.1);          // f32(0.9)
    const float INVM   = (float)(1.0 / (1.0 - 0.1));  // f32(1.111...)
    float a = out[idx];
    out[idx] = (u < P_KEEP) ? a * INVM : 0.0f;
}

extern "C" void kernel_launch(void* const* d_in, const int* in_sizes, int n_in,
                              void* d_out, int out_size, void* d_ws, size_t ws_size,
                              hipStream_t stream) {
    const float* ue   = (const float*)d_in[0];
    const float* ie   = (const float*)d_in[1];
    const float* vals = (const float*)d_in[2];
    const int*   rows = (const int*)d_in[3];
    const int*   cols = (const int*)d_in[4];
    float* out = (float*)d_out;
    float* vws = (float*)d_ws;
    const bool use_ws = ws_size >= (size_t)NNZ * sizeof(float);

    init_kernel<<<(NT * 16 + 255) / 256, 256, 0, stream>>>(
        (const float4*)ue, (const float4*)ie, (float4*)out);

    for (int h = 0; h < NHOPS; ++h) {
        // key derivation (host, deterministic):
        // kf = fold_in(key(42), h);  ke = split[0];  km = split[1]
        uint32_t kf0, kf1, ke0, ke1, km0, km1;
        tf2x32(0u, 42u, 0u, (uint32_t)h, kf0, kf1);
        tf2x32(kf0, kf1, 0u, 0u, ke0, ke1);
        tf2x32(kf0, kf1, 0u, 1u, km0, km1);

        if (use_ws) {
            edge_drop_kernel<<<(NNZ + 255) / 256, 256, 0, stream>>>(vals, vws, ke0, ke1);
            spmm_kernel<<<(NNZ + 3) / 4, 256, 0, stream>>>(vws, rows, cols, out, h);
        } else {
            spmm_inline_kernel<<<(NNZ + 3) / 4, 256, 0, stream>>>(
                vals, rows, cols, out, h, ke0, ke1);
        }
        mess_drop_kernel<<<(NT * D + 255) / 256, 256, 0, stream>>>(out, h, km0, km1);
    }
}

// Round 2
// 844.348 us; speedup vs baseline: 1.0019x; 1.0019x over previous
//
#include <hip/hip_runtime.h>
#include <stdint.h>

#define NU 100000
#define NI 200000
#define NT 300000          // NU + NI
#define D 64
#define NNZ 1200000
#define NHOPS 3
#define SL 4               // slices per row = NHOPS+1
#define ROWF (SL * D)      // 256 floats per output row
#define SCAN_BLK 1024

__host__ __device__ __forceinline__ uint32_t rotl32(uint32_t x, int r) {
    return (x << r) | (x >> (32 - r));
}

// Threefry-2x32, 20 rounds — matches jax._src.prng.threefry2x32
__host__ __device__ inline void tf2x32(uint32_t k0, uint32_t k1,
                                       uint32_t x0, uint32_t x1,
                                       uint32_t& o0, uint32_t& o1) {
    uint32_t ks0 = k0, ks1 = k1, ks2 = k0 ^ k1 ^ 0x1BD11BDAu;
    x0 += ks0; x1 += ks1;
#define RND(r) { x0 += x1; x1 = rotl32(x1, r); x1 ^= x0; }
    RND(13) RND(15) RND(26) RND(6)
    x0 += ks1; x1 += ks2 + 1u;
    RND(17) RND(29) RND(16) RND(24)
    x0 += ks2; x1 += ks0 + 2u;
    RND(13) RND(15) RND(26) RND(6)
    x0 += ks0; x1 += ks1 + 3u;
    RND(17) RND(29) RND(16) RND(24)
    x0 += ks1; x1 += ks2 + 4u;
    RND(13) RND(15) RND(26) RND(6)
    o0 = x0 + ks2; o1 = x1 + ks0 + 5u;
#undef RND
}

__device__ __forceinline__ uint32_t rbits(uint32_t k0, uint32_t k1, uint32_t j) {
    uint32_t o0, o1;
    tf2x32(k0, k1, 0u, j, o0, o1);
    return o0 ^ o1;
}

__device__ __forceinline__ float u01(uint32_t bits) {
    return __uint_as_float((bits >> 9) | 0x3f800000u) - 1.0f;
}

// ------------------------- CSR-path kernels -------------------------

// hop-0 copy only (slices 1..3 are fully overwritten by spmm_csr)
__global__ void init0_kernel(const float4* __restrict__ ue,
                             const float4* __restrict__ ie,
                             float4* __restrict__ out) {
    int gid = blockIdx.x * blockDim.x + threadIdx.x;   // over NT*16
    if (gid >= NT * 16) return;
    int n = gid >> 4, q = gid & 15;
    float4 v = (n < NU) ? ue[n * 16 + q] : ie[(n - NU) * 16 + q];
    out[(size_t)n * 64 + q] = v;
}

__global__ void zero_kernel(int* __restrict__ p, int n) {
    int i = blockIdx.x * blockDim.x + threadIdx.x;
    if (i < n) p[i] = 0;
}

__global__ void hist_kernel(const int* __restrict__ rows, int* __restrict__ rp) {
    int e = blockIdx.x * blockDim.x + threadIdx.x;
    if (e < NNZ) atomicAdd(&rp[rows[e] + 1], 1);
}

// inclusive scan of rp[0..n) per 1024-block; block totals to partials[]
__global__ void scan_block_kernel(int* __restrict__ rp, int* __restrict__ partials, int n) {
    __shared__ int wsum[16];
    int tid = threadIdx.x, idx = blockIdx.x * SCAN_BLK + tid;
    int v = (idx < n) ? rp[idx] : 0;
    int lane = tid & 63, wv = tid >> 6;
    for (int o = 1; o < 64; o <<= 1) { int t = __shfl_up(v, o, 64); if (lane >= o) v += t; }
    if (lane == 63) wsum[wv] = v;
    __syncthreads();
    if (wv == 0) {
        int s = (lane < 16) ? wsum[lane] : 0;
        for (int o = 1; o < 16; o <<= 1) { int t = __shfl_up(s, o, 64); if (lane >= o) s += t; }
        if (lane < 16) wsum[lane] = s;
    }
    __syncthreads();
    int off = (wv > 0) ? wsum[wv - 1] : 0;
    v += off;
    if (idx < n) rp[idx] = v;
    if (tid == SCAN_BLK - 1) partials[blockIdx.x] = wsum[15];
}

// exclusive scan of partials (single block, nb <= 512)
__global__ void scan_partials_kernel(int* __restrict__ partials, int nb) {
    __shared__ int wsum[8];
    int tid = threadIdx.x;
    int v = (tid < nb) ? partials[tid] : 0;
    int own = v;
    int lane = tid & 63, wv = tid >> 6;
    for (int o = 1; o < 64; o <<= 1) { int t = __shfl_up(v, o, 64); if (lane >= o) v += t; }
    if (lane == 63) wsum[wv] = v;
    __syncthreads();
    if (wv == 0) {
        int s = (lane < 8) ? wsum[lane] : 0;
        for (int o = 1; o < 8; o <<= 1) { int t = __shfl_up(s, o, 64); if (lane >= o) s += t; }
        if (lane < 8) wsum[lane] = s;
    }
    __syncthreads();
    int off = (wv > 0) ? wsum[wv - 1] : 0;
    if (tid < nb) partials[tid] = v + off - own;
}

__global__ void add_offsets_kernel(int* __restrict__ rp, const int* __restrict__ partials, int n) {
    int idx = blockIdx.x * SCAN_BLK + threadIdx.x;
    if (idx < n && blockIdx.x > 0) rp[idx] += partials[blockIdx.x];
}

// scatter edges into CSR order: edges[pos] = {col, eid, val_bits, 0}
__global__ void scatter_kernel(const int* __restrict__ rows, const int* __restrict__ cols,
                               const float* __restrict__ vals,
                               const int* __restrict__ rp, int* __restrict__ cur,
                               int4* __restrict__ edges) {
    int e = blockIdx.x * blockDim.x + threadIdx.x;
    if (e >= NNZ) return;
    int r = rows[e];
    int pos = rp[r] + atomicAdd(&cur[r], 1);
    edges[pos] = make_int4(cols[e], e, __float_as_int(vals[e]), 0);
}

// one wave per destination row; edge-drop RNG inline; mess-drop fused
__global__ void spmm_csr_kernel(const int* __restrict__ rp,
                                const int4* __restrict__ edges,
                                float* __restrict__ out, int hop,
                                uint32_t ke0, uint32_t ke1,
                                uint32_t km0, uint32_t km1) {
    int w    = (blockIdx.x * blockDim.x + threadIdx.x) >> 6;
    int lane = threadIdx.x & 63;
    if (w >= NT) return;
    int s = rp[w], epos = rp[w + 1];
    float acc = 0.0f;
    for (int j = s; j < epos; ++j) {
        int4 ed = edges[j];
        float u = u01(rbits(ke0, ke1, (uint32_t)ed.y));
        if (u < 0.5f) continue;                       // dropped edge
        float ve = __int_as_float(ed.z);
        acc += ve * out[(size_t)ed.x * ROWF + hop * D + lane];
    }
    acc *= 2.0f;                                      // 1/(1-0.5), exact pow2 scale
    // fused message dropout on flat index w*64+lane
    const float P_KEEP = (float)(1.0 - 0.1);
    const float INVM   = (float)(1.0 / (1.0 - 0.1));
    float um = u01(rbits(km0, km1, (uint32_t)(w * D + lane)));
    acc = (um < P_KEEP) ? acc * INVM : 0.0f;
    out[(size_t)w * ROWF + (hop + 1) * D + lane] = acc;
}

// ------------------------- fallback (round-1) kernels -------------------------

__global__ void init_kernel(const float4* __restrict__ ue,
                            const float4* __restrict__ ie,
                            float4* __restrict__ out) {
    int gid = blockIdx.x * blockDim.x + threadIdx.x;
    if (gid >= NT * 16) return;
    int n = gid >> 4, q = gid & 15;
    float4 v = (n < NU) ? ue[n * 16 + q] : ie[(n - NU) * 16 + q];
    float4 z = make_float4(0.f, 0.f, 0.f, 0.f);
    float4* row = out + (size_t)n * 64;
    row[q]      = v;
    row[16 + q] = z;
    row[32 + q] = z;
    row[48 + q] = z;
}

__global__ void edge_drop_kernel(const float* __restrict__ vals,
                                 float* __restrict__ v,
                                 uint32_t ke0, uint32_t ke1) {
    int e = blockIdx.x * blockDim.x + threadIdx.x;
    if (e >= NNZ) return;
    float u = u01(rbits(ke0, ke1, (uint32_t)e));
    v[e] = (u >= 0.5f) ? vals[e] * 2.0f : 0.0f;
}

__global__ void spmm_kernel(const float* __restrict__ v,
                            const int* __restrict__ rows,
                            const int* __restrict__ cols,
                            float* __restrict__ out, int hop) {
    int wid  = (blockIdx.x * blockDim.x + threadIdx.x) >> 6;
    int lane = threadIdx.x & 63;
    if (wid >= NNZ) return;
    float ve = v[wid];
    if (ve == 0.0f) return;
    int r = rows[wid], c = cols[wid];
    float x = out[c * ROWF + hop * D + lane];
    unsafeAtomicAdd(&out[r * ROWF + (hop + 1) * D + lane], ve * x);
}

__global__ void spmm_inline_kernel(const float* __restrict__ vals,
                                   const int* __restrict__ rows,
                                   const int* __restrict__ cols,
                                   float* __restrict__ out, int hop,
                                   uint32_t ke0, uint32_t ke1) {
    int wid  = (blockIdx.x * blockDim.x + threadIdx.x) >> 6;
    int lane = threadIdx.x & 63;
    if (wid >= NNZ) return;
    float u = u01(rbits(ke0, ke1, (uint32_t)wid));
    if (u < 0.5f) return;
    float ve = vals[wid] * 2.0f;
    int r = rows[wid], c = cols[wid];
    float x = out[c * ROWF + hop * D + lane];
    unsafeAtomicAdd(&out[r * ROWF + (hop + 1) * D + lane], ve * x);
}

__global__ void mess_drop_kernel(float* __restrict__ out, int hop,
                                 uint32_t km0, uint32_t km1) {
    int j = blockIdx.x * blockDim.x + threadIdx.x;
    if (j >= NT * D) return;
    float u = u01(rbits(km0, km1, (uint32_t)j));
    int n = j >> 6, d = j & 63;
    int idx = n * ROWF + (hop + 1) * D + d;
    const float P_KEEP = (float)(1.0 - 0.1);
    const float INVM   = (float)(1.0 / (1.0 - 0.1));
    float a = out[idx];
    out[idx] = (u < P_KEEP) ? a * INVM : 0.0f;
}

// ------------------------- launch -------------------------

extern "C" void kernel_launch(void* const* d_in, const int* in_sizes, int n_in,
                              void* d_out, int out_size, void* d_ws, size_t ws_size,
                              hipStream_t stream) {
    const float* ue   = (const float*)d_in[0];
    const float* ie   = (const float*)d_in[1];
    const float* vals = (const float*)d_in[2];
    const int*   rows = (const int*)d_in[3];
    const int*   cols = (const int*)d_in[4];
    float* out = (float*)d_out;

    // ws layout for CSR path
    const size_t off_rp    = 0;                                  // (NT+1) ints
    const size_t off_cur   = 1200016;                            // NT ints
    const size_t off_edges = 2400016;                            // NNZ int4 (16B-aligned)
    const size_t need      = off_edges + (size_t)NNZ * 16;       // ~21.6 MB

    uint32_t kf0, kf1;
    uint32_t ke0[NHOPS], ke1[NHOPS], km0[NHOPS], km1[NHOPS];
    for (int h = 0; h < NHOPS; ++h) {
        tf2x32(0u, 42u, 0u, (uint32_t)h, kf0, kf1);
        tf2x32(kf0, kf1, 0u, 0u, ke0[h], ke1[h]);
        tf2x32(kf0, kf1, 0u, 1u, km0[h], km1[h]);
    }

    if (ws_size >= need) {
        int*  rp    = (int*)((char*)d_ws + off_rp);
        int*  cur   = (int*)((char*)d_ws + off_cur);
        int4* edges = (int4*)((char*)d_ws + off_edges);
        int*  partials = cur;  // reuse cur buffer region? NO — cur needed. Use tail of rp region:
        // partials needs ~294 ints; place it right after edges? edges is last. Use a slice of cur
        // BEFORE cur is zeroed/used: scan runs before cur is needed, but zero_kernel zeroes cur
        // after scan. Safe ordering below.
        partials = cur;        // 294 ints, overwritten/zeroed later before scatter

        const int n = NT + 1;
        const int nscan = (n + SCAN_BLK - 1) / SCAN_BLK;   // 294

        init0_kernel<<<(NT * 16 + 255) / 256, 256, 0, stream>>>(
            (const float4*)ue, (const float4*)ie, (float4*)out);

        zero_kernel<<<(n + 255) / 256, 256, 0, stream>>>(rp, n);
        hist_kernel<<<(NNZ + 255) / 256, 256, 0, stream>>>(rows, rp);
        scan_block_kernel<<<nscan, SCAN_BLK, 0, stream>>>(rp, partials, n);
        scan_partials_kernel<<<1, 512, 0, stream>>>(partials, nscan);
        add_offsets_kernel<<<nscan, SCAN_BLK, 0, stream>>>(rp, partials, n);
        zero_kernel<<<(NT + 255) / 256, 256, 0, stream>>>(cur, NT);
        scatter_kernel<<<(NNZ + 255) / 256, 256, 0, stream>>>(rows, cols, vals, rp, cur, edges);

        for (int h = 0; h < NHOPS; ++h) {
            spmm_csr_kernel<<<(NT + 3) / 4, 256, 0, stream>>>(
                rp, edges, out, h, ke0[h], ke1[h], km0[h], km1[h]);
        }
    } else {
        float* vws = (float*)d_ws;
        const bool use_ws = ws_size >= (size_t)NNZ * sizeof(float);

        init_kernel<<<(NT * 16 + 255) / 256, 256, 0, stream>>>(
            (const float4*)ue, (const float4*)ie, (float4*)out);

        for (int h = 0; h < NHOPS; ++h) {
            if (use_ws) {
                edge_drop_kernel<<<(NNZ + 255) / 256, 256, 0, stream>>>(vals, vws, ke0[h], ke1[h]);
                spmm_kernel<<<(NNZ + 3) / 4, 256, 0, stream>>>(vws, rows, cols, out, h);
            } else {
                spmm_inline_kernel<<<(NNZ + 3) / 4, 256, 0, stream>>>(
                    vals, rows, cols, out, h, ke0[h], ke1[h]);
            }
            mess_drop_kernel<<<(NT * D + 255) / 256, 256, 0, stream>>>(out, h, km0[h], km1[h]);
        }
    }
}

// Round 3
// 498.315 us; speedup vs baseline: 1.6976x; 1.6944x over previous
//
#include <hip/hip_runtime.h>
#include <stdint.h>

#define NU 100000
#define NI 200000
#define NT 300000          // NU + NI
#define D 64
#define NNZ 1200000
#define NHOPS 3
#define SL 4               // slices per row = NHOPS+1
#define ROWF (SL * D)      // 256 floats per output row
#define SCAN_BLK 1024

__host__ __device__ __forceinline__ uint32_t rotl32(uint32_t x, int r) {
    return (x << r) | (x >> (32 - r));
}

// Threefry-2x32, 20 rounds — matches jax._src.prng.threefry2x32
__host__ __device__ inline void tf2x32(uint32_t k0, uint32_t k1,
                                       uint32_t x0, uint32_t x1,
                                       uint32_t& o0, uint32_t& o1) {
    uint32_t ks0 = k0, ks1 = k1, ks2 = k0 ^ k1 ^ 0x1BD11BDAu;
    x0 += ks0; x1 += ks1;
#define RND(r) { x0 += x1; x1 = rotl32(x1, r); x1 ^= x0; }
    RND(13) RND(15) RND(26) RND(6)
    x0 += ks1; x1 += ks2 + 1u;
    RND(17) RND(29) RND(16) RND(24)
    x0 += ks2; x1 += ks0 + 2u;
    RND(13) RND(15) RND(26) RND(6)
    x0 += ks0; x1 += ks1 + 3u;
    RND(17) RND(29) RND(16) RND(24)
    x0 += ks1; x1 += ks2 + 4u;
    RND(13) RND(15) RND(26) RND(6)
    o0 = x0 + ks2; o1 = x1 + ks0 + 5u;
#undef RND
}

__device__ __forceinline__ uint32_t rbits(uint32_t k0, uint32_t k1, uint32_t j) {
    uint32_t o0, o1;
    tf2x32(k0, k1, 0u, j, o0, o1);
    return o0 ^ o1;
}

__device__ __forceinline__ float u01(uint32_t bits) {
    return __uint_as_float((bits >> 9) | 0x3f800000u) - 1.0f;
}

// ------------------------- CSR-path kernels -------------------------

// hop-0 copy only (slices 1..3 are fully overwritten by spmm_csr)
__global__ void init0_kernel(const float4* __restrict__ ue,
                             const float4* __restrict__ ie,
                             float4* __restrict__ out) {
    int gid = blockIdx.x * blockDim.x + threadIdx.x;   // over NT*16
    if (gid >= NT * 16) return;
    int n = gid >> 4, q = gid & 15;
    float4 v = (n < NU) ? ue[n * 16 + q] : ie[(n - NU) * 16 + q];
    out[(size_t)n * 64 + q] = v;
}

__global__ void zero_kernel(int* __restrict__ p, int n) {
    int i = blockIdx.x * blockDim.x + threadIdx.x;
    if (i < n) p[i] = 0;
}

__global__ void hist_kernel(const int* __restrict__ rows, int* __restrict__ rp) {
    int e = blockIdx.x * blockDim.x + threadIdx.x;
    if (e < NNZ) atomicAdd(&rp[rows[e] + 1], 1);
}

// inclusive scan of rp[0..n) per 1024-block; block totals to partials[]
__global__ void scan_block_kernel(int* __restrict__ rp, int* __restrict__ partials, int n) {
    __shared__ int wsum[16];
    int tid = threadIdx.x, idx = blockIdx.x * SCAN_BLK + tid;
    int v = (idx < n) ? rp[idx] : 0;
    int lane = tid & 63, wv = tid >> 6;
    for (int o = 1; o < 64; o <<= 1) { int t = __shfl_up(v, o, 64); if (lane >= o) v += t; }
    if (lane == 63) wsum[wv] = v;
    __syncthreads();
    if (wv == 0) {
        int s = (lane < 16) ? wsum[lane] : 0;
        for (int o = 1; o < 16; o <<= 1) { int t = __shfl_up(s, o, 64); if (lane >= o) s += t; }
        if (lane < 16) wsum[lane] = s;
    }
    __syncthreads();
    int off = (wv > 0) ? wsum[wv - 1] : 0;
    v += off;
    if (idx < n) rp[idx] = v;
    if (tid == SCAN_BLK - 1) partials[blockIdx.x] = wsum[15];
}

// exclusive scan of partials (single block, nb <= 512)
__global__ void scan_partials_kernel(int* __restrict__ partials, int nb) {
    __shared__ int wsum[8];
    int tid = threadIdx.x;
    int v = (tid < nb) ? partials[tid] : 0;
    int own = v;
    int lane = tid & 63, wv = tid >> 6;
    for (int o = 1; o < 64; o <<= 1) { int t = __shfl_up(v, o, 64); if (lane >= o) v += t; }
    if (lane == 63) wsum[wv] = v;
    __syncthreads();
    if (wv == 0) {
        int s = (lane < 8) ? wsum[lane] : 0;
        for (int o = 1; o < 8; o <<= 1) { int t = __shfl_up(s, o, 64); if (lane >= o) s += t; }
        if (lane < 8) wsum[lane] = s;
    }
    __syncthreads();
    int off = (wv > 0) ? wsum[wv - 1] : 0;
    if (tid < nb) partials[tid] = v + off - own;
}

__global__ void add_offsets_kernel(int* __restrict__ rp, const int* __restrict__ partials, int n) {
    int idx = blockIdx.x * SCAN_BLK + threadIdx.x;
    if (idx < n && blockIdx.x > 0) rp[idx] += partials[blockIdx.x];
}

// scatter edges into CSR order: ecol[pos]=col, epair[pos]={eid, val_bits}
__global__ void scatter_kernel(const int* __restrict__ rows, const int* __restrict__ cols,
                               const float* __restrict__ vals,
                               const int* __restrict__ rp, int* __restrict__ cur,
                               int* __restrict__ ecol, int2* __restrict__ epair) {
    int e = blockIdx.x * blockDim.x + threadIdx.x;
    if (e >= NNZ) return;
    int r = rows[e];
    int pos = rp[r] + atomicAdd(&cur[r], 1);
    ecol[pos]  = cols[e];
    epair[pos] = make_int2(e, __float_as_int(vals[e]));
}

// per-hop edge coefficient: vcsr[pos] = keep(eid) ? val*2 : 0
__global__ void prep_hop_kernel(const int2* __restrict__ epair,
                                float* __restrict__ vcsr,
                                uint32_t ke0, uint32_t ke1) {
    int p = blockIdx.x * blockDim.x + threadIdx.x;
    if (p >= NNZ) return;
    int2 ev = epair[p];
    float u = u01(rbits(ke0, ke1, (uint32_t)ev.x));
    vcsr[p] = (u >= 0.5f) ? __int_as_float(ev.y) * 2.0f : 0.0f;
}

// one wave per destination row; no edge RNG; mess-drop fused
__global__ void spmm_csr_kernel(const int* __restrict__ rp,
                                const int* __restrict__ ecol,
                                const float* __restrict__ vcsr,
                                float* __restrict__ out, int hop,
                                uint32_t km0, uint32_t km1) {
    int w    = (blockIdx.x * blockDim.x + threadIdx.x) >> 6;
    int lane = threadIdx.x & 63;
    if (w >= NT) return;
    int s = rp[w], epos = rp[w + 1];
    int len = epos - s;

    // cooperative preload of the row's edge list (rows are ~Poisson(4); len>64 ~never)
    float vl = 0.0f; int cl = 0;
    if (lane < len) { vl = vcsr[s + lane]; cl = ecol[s + lane]; }

    float acc = 0.0f;
    int m = (len < 64) ? len : 64;
    for (int j = 0; j < m; ++j) {
        float ve = __shfl(vl, j, 64);        // wave-uniform
        if (ve != 0.0f) {
            int c = __shfl(cl, j, 64);
            acc += ve * out[(size_t)c * ROWF + hop * D + lane];
        }
    }
    for (int j = s + 64; j < epos; ++j) {    // overflow guard (cold)
        float ve = vcsr[j];
        if (ve == 0.0f) continue;
        acc += ve * out[(size_t)ecol[j] * ROWF + hop * D + lane];
    }

    // fused message dropout on flat index w*64+lane
    const float P_KEEP = (float)(1.0 - 0.1);
    const float INVM   = (float)(1.0 / (1.0 - 0.1));
    float um = u01(rbits(km0, km1, (uint32_t)(w * D + lane)));
    acc = (um < P_KEEP) ? acc * INVM : 0.0f;
    out[(size_t)w * ROWF + (hop + 1) * D + lane] = acc;
}

// ------------------------- fallback (round-1) kernels -------------------------

__global__ void init_kernel(const float4* __restrict__ ue,
                            const float4* __restrict__ ie,
                            float4* __restrict__ out) {
    int gid = blockIdx.x * blockDim.x + threadIdx.x;
    if (gid >= NT * 16) return;
    int n = gid >> 4, q = gid & 15;
    float4 v = (n < NU) ? ue[n * 16 + q] : ie[(n - NU) * 16 + q];
    float4 z = make_float4(0.f, 0.f, 0.f, 0.f);
    float4* row = out + (size_t)n * 64;
    row[q]      = v;
    row[16 + q] = z;
    row[32 + q] = z;
    row[48 + q] = z;
}

__global__ void spmm_inline_kernel(const float* __restrict__ vals,
                                   const int* __restrict__ rows,
                                   const int* __restrict__ cols,
                                   float* __restrict__ out, int hop,
                                   uint32_t ke0, uint32_t ke1) {
    int wid  = (blockIdx.x * blockDim.x + threadIdx.x) >> 6;
    int lane = threadIdx.x & 63;
    if (wid >= NNZ) return;
    float u = u01(rbits(ke0, ke1, (uint32_t)wid));
    if (u < 0.5f) return;
    float ve = vals[wid] * 2.0f;
    int r = rows[wid], c = cols[wid];
    float x = out[c * ROWF + hop * D + lane];
    unsafeAtomicAdd(&out[r * ROWF + (hop + 1) * D + lane], ve * x);
}

__global__ void mess_drop_kernel(float* __restrict__ out, int hop,
                                 uint32_t km0, uint32_t km1) {
    int j = blockIdx.x * blockDim.x + threadIdx.x;
    if (j >= NT * D) return;
    float u = u01(rbits(km0, km1, (uint32_t)j));
    int n = j >> 6, d = j & 63;
    int idx = n * ROWF + (hop + 1) * D + d;
    const float P_KEEP = (float)(1.0 - 0.1);
    const float INVM   = (float)(1.0 / (1.0 - 0.1));
    float a = out[idx];
    out[idx] = (u < P_KEEP) ? a * INVM : 0.0f;
}

// ------------------------- launch -------------------------

extern "C" void kernel_launch(void* const* d_in, const int* in_sizes, int n_in,
                              void* d_out, int out_size, void* d_ws, size_t ws_size,
                              hipStream_t stream) {
    const float* ue   = (const float*)d_in[0];
    const float* ie   = (const float*)d_in[1];
    const float* vals = (const float*)d_in[2];
    const int*   rows = (const int*)d_in[3];
    const int*   cols = (const int*)d_in[4];
    float* out = (float*)d_out;

    // ws layout for CSR path (total 21,600,016 B — same as proven round-2 size)
    const size_t off_rp    = 0;                                   // (NT+1) ints
    const size_t off_cur   = 1200016;                             // NT ints
    const size_t off_ecol  = 2400016;                             // NNZ ints
    const size_t off_epair = 7200016;                             // NNZ int2 {eid,val}
    const size_t off_vcsr  = 16800016;                            // NNZ floats
    const size_t need      = off_vcsr + (size_t)NNZ * 4;          // 21,600,016

    uint32_t kf0, kf1;
    uint32_t ke0[NHOPS], ke1[NHOPS], km0[NHOPS], km1[NHOPS];
    for (int h = 0; h < NHOPS; ++h) {
        tf2x32(0u, 42u, 0u, (uint32_t)h, kf0, kf1);
        tf2x32(kf0, kf1, 0u, 0u, ke0[h], ke1[h]);
        tf2x32(kf0, kf1, 0u, 1u, km0[h], km1[h]);
    }

    if (ws_size >= need) {
        int*   rp    = (int*)((char*)d_ws + off_rp);
        int*   cur   = (int*)((char*)d_ws + off_cur);
        int*   ecol  = (int*)((char*)d_ws + off_ecol);
        int2*  epair = (int2*)((char*)d_ws + off_epair);
        float* vcsr  = (float*)((char*)d_ws + off_vcsr);
        int*   partials = cur;   // 294 ints; used during scan, re-zeroed before scatter

        const int n = NT + 1;
        const int nscan = (n + SCAN_BLK - 1) / SCAN_BLK;   // 294

        init0_kernel<<<(NT * 16 + 255) / 256, 256, 0, stream>>>(
            (const float4*)ue, (const float4*)ie, (float4*)out);

        zero_kernel<<<(n + 255) / 256, 256, 0, stream>>>(rp, n);
        hist_kernel<<<(NNZ + 255) / 256, 256, 0, stream>>>(rows, rp);
        scan_block_kernel<<<nscan, SCAN_BLK, 0, stream>>>(rp, partials, n);
        scan_partials_kernel<<<1, 512, 0, stream>>>(partials, nscan);
        add_offsets_kernel<<<nscan, SCAN_BLK, 0, stream>>>(rp, partials, n);
        zero_kernel<<<(NT + 255) / 256, 256, 0, stream>>>(cur, NT);
        scatter_kernel<<<(NNZ + 255) / 256, 256, 0, stream>>>(rows, cols, vals, rp, cur,
                                                              ecol, epair);

        for (int h = 0; h < NHOPS; ++h) {
            prep_hop_kernel<<<(NNZ + 255) / 256, 256, 0, stream>>>(epair, vcsr, ke0[h], ke1[h]);
            spmm_csr_kernel<<<(NT + 3) / 4, 256, 0, stream>>>(
                rp, ecol, vcsr, out, h, km0[h], km1[h]);
        }
    } else {
        init_kernel<<<(NT * 16 + 255) / 256, 256, 0, stream>>>(
            (const float4*)ue, (const float4*)ie, (float4*)out);

        for (int h = 0; h < NHOPS; ++h) {
            spmm_inline_kernel<<<(NNZ + 3) / 4, 256, 0, stream>>>(
                vals, rows, cols, out, h, ke0[h], ke1[h]);
            mess_drop_kernel<<<(NT * D + 255) / 256, 256, 0, stream>>>(out, h, km0[h], km1[h]);
        }
    }
}

// Round 4
// 491.294 us; speedup vs baseline: 1.7219x; 1.0143x over previous
//
#include <hip/hip_runtime.h>
#include <stdint.h>

#define NU 100000
#define NI 200000
#define NT 300000          // NU + NI
#define D 64
#define NNZ 1200000
#define NHOPS 3
#define SL 4               // slices per row = NHOPS+1
#define ROWF (SL * D)      // 256 floats per output row
#define SCAN_BLK 1024

__host__ __device__ __forceinline__ uint32_t rotl32(uint32_t x, int r) {
    return (x << r) | (x >> (32 - r));
}

// Threefry-2x32, 20 rounds — matches jax._src.prng.threefry2x32
__host__ __device__ inline void tf2x32(uint32_t k0, uint32_t k1,
                                       uint32_t x0, uint32_t x1,
                                       uint32_t& o0, uint32_t& o1) {
    uint32_t ks0 = k0, ks1 = k1, ks2 = k0 ^ k1 ^ 0x1BD11BDAu;
    x0 += ks0; x1 += ks1;
#define RND(r) { x0 += x1; x1 = rotl32(x1, r); x1 ^= x0; }
    RND(13) RND(15) RND(26) RND(6)
    x0 += ks1; x1 += ks2 + 1u;
    RND(17) RND(29) RND(16) RND(24)
    x0 += ks2; x1 += ks0 + 2u;
    RND(13) RND(15) RND(26) RND(6)
    x0 += ks0; x1 += ks1 + 3u;
    RND(17) RND(29) RND(16) RND(24)
    x0 += ks1; x1 += ks2 + 4u;
    RND(13) RND(15) RND(26) RND(6)
    o0 = x0 + ks2; o1 = x1 + ks0 + 5u;
#undef RND
}

__device__ __forceinline__ uint32_t rbits(uint32_t k0, uint32_t k1, uint32_t j) {
    uint32_t o0, o1;
    tf2x32(k0, k1, 0u, j, o0, o1);
    return o0 ^ o1;
}

__device__ __forceinline__ float u01(uint32_t bits) {
    return __uint_as_float((bits >> 9) | 0x3f800000u) - 1.0f;
}

// ------------------------- shared CSR-build kernels -------------------------

__global__ void zero_kernel(int* __restrict__ p, int n) {
    int i = blockIdx.x * blockDim.x + threadIdx.x;
    if (i < n) p[i] = 0;
}

__global__ void hist_kernel(const int* __restrict__ rows, int* __restrict__ rp) {
    int e = blockIdx.x * blockDim.x + threadIdx.x;
    if (e < NNZ) atomicAdd(&rp[rows[e] + 1], 1);
}

__global__ void scan_block_kernel(int* __restrict__ rp, int* __restrict__ partials, int n) {
    __shared__ int wsum[16];
    int tid = threadIdx.x, idx = blockIdx.x * SCAN_BLK + tid;
    int v = (idx < n) ? rp[idx] : 0;
    int lane = tid & 63, wv = tid >> 6;
    for (int o = 1; o < 64; o <<= 1) { int t = __shfl_up(v, o, 64); if (lane >= o) v += t; }
    if (lane == 63) wsum[wv] = v;
    __syncthreads();
    if (wv == 0) {
        int s = (lane < 16) ? wsum[lane] : 0;
        for (int o = 1; o < 16; o <<= 1) { int t = __shfl_up(s, o, 64); if (lane >= o) s += t; }
        if (lane < 16) wsum[lane] = s;
    }
    __syncthreads();
    int off = (wv > 0) ? wsum[wv - 1] : 0;
    v += off;
    if (idx < n) rp[idx] = v;
    if (tid == SCAN_BLK - 1) partials[blockIdx.x] = wsum[15];
}

__global__ void scan_partials_kernel(int* __restrict__ partials, int nb) {
    __shared__ int wsum[8];
    int tid = threadIdx.x;
    int v = (tid < nb) ? partials[tid] : 0;
    int own = v;
    int lane = tid & 63, wv = tid >> 6;
    for (int o = 1; o < 64; o <<= 1) { int t = __shfl_up(v, o, 64); if (lane >= o) v += t; }
    if (lane == 63) wsum[wv] = v;
    __syncthreads();
    if (wv == 0) {
        int s = (lane < 8) ? wsum[lane] : 0;
        for (int o = 1; o < 8; o <<= 1) { int t = __shfl_up(s, o, 64); if (lane >= o) s += t; }
        if (lane < 8) wsum[lane] = s;
    }
    __syncthreads();
    int off = (wv > 0) ? wsum[wv - 1] : 0;
    if (tid < nb) partials[tid] = v + off - own;
}

__global__ void add_offsets_kernel(int* __restrict__ rp, const int* __restrict__ partials, int n) {
    int idx = blockIdx.x * SCAN_BLK + threadIdx.x;
    if (idx < n && blockIdx.x > 0) rp[idx] += partials[blockIdx.x];
}

__global__ void scatter_kernel(const int* __restrict__ rows, const int* __restrict__ cols,
                               const float* __restrict__ vals,
                               const int* __restrict__ rp, int* __restrict__ cur,
                               int* __restrict__ ecol, int2* __restrict__ epair) {
    int e = blockIdx.x * blockDim.x + threadIdx.x;
    if (e >= NNZ) return;
    int r = rows[e];
    int pos = rp[r] + atomicAdd(&cur[r], 1);
    ecol[pos]  = cols[e];
    epair[pos] = make_int2(e, __float_as_int(vals[e]));
}

// ------------------------- new fast path -------------------------

// thread per row: compact kept edges to kpair {col, val_bits}; kinfo = {start, count}
__global__ void prep2_kernel(const int* __restrict__ rp,
                             const int* __restrict__ ecol,
                             const int2* __restrict__ epair,
                             int2* __restrict__ kpair,
                             int2* __restrict__ kinfo,
                             uint32_t ke0, uint32_t ke1) {
    int r = blockIdx.x * blockDim.x + threadIdx.x;
    if (r >= NT) return;
    int s = rp[r], e = rp[r + 1];
    int cnt = 0;
    for (int j = s; j < e; ++j) {
        int2 ev = epair[j];
        float u = u01(rbits(ke0, ke1, (uint32_t)ev.x));
        if (u >= 0.5f) {
            float v2 = __int_as_float(ev.y) * 2.0f;
            kpair[s + cnt] = make_int2(ecol[j], __float_as_int(v2));
            ++cnt;
        }
    }
    kinfo[r] = make_int2(s, cnt);
}

// one wave per destination row; batched unrolled gathers; mess-drop fused.
// H0: gather from ue/ie directly and also write slice 0 (fuses init).
template <int H0>
__global__ void spmm2_kernel(const int2* __restrict__ kinfo,
                             const int2* __restrict__ kpair,
                             const float* __restrict__ ue,
                             const float* __restrict__ ie,
                             float* __restrict__ out, int hop,
                             uint32_t km0, uint32_t km1) {
    int w    = (blockIdx.x * blockDim.x + threadIdx.x) >> 6;
    int lane = threadIdx.x & 63;
    if (w >= NT) return;
    int2 si = kinfo[w];
    int s = si.x, m = si.y;

    if (H0) {  // fused hop-0 slice copy (own row)
        float e0 = (w < NU) ? ue[(size_t)w * D + lane] : ie[(size_t)(w - NU) * D + lane];
        out[(size_t)w * ROWF + lane] = e0;
    }

    // cooperative preload of kept edges (one 8B load per lane)
    float vl = 0.0f; int cl = 0;
    int mm = (m < 64) ? m : 64;
    if (lane < mm) {
        int2 kp = kpair[s + lane];
        cl = kp.x; vl = __int_as_float(kp.y);
    }

    float acc = 0.0f;
    int j = 0;
    while (j < mm) {
        float vv[4]; float g[4];
        #pragma unroll
        for (int k = 0; k < 4; ++k) {
            vv[k] = __shfl(vl, j + k, 64);          // 0 for slots >= mm
            int ck = __shfl(cl, j + k, 64);         // 0 for slots >= mm (valid addr)
            if (H0) {
                g[k] = (ck < NU) ? ue[(size_t)ck * D + lane]
                                 : ie[(size_t)(ck - NU) * D + lane];
            } else {
                g[k] = out[(size_t)ck * ROWF + (size_t)hop * D + lane];
            }
        }
        #pragma unroll
        for (int k = 0; k < 4; ++k) acc += vv[k] * g[k];
        j += 4;
    }
    // cold overflow guard (m > 64 never happens for this input, kept for safety)
    for (int j2 = s + 64; j2 < s + m; ++j2) {
        int2 kp = kpair[j2];
        int ck = kp.x;
        float src;
        if (H0) src = (ck < NU) ? ue[(size_t)ck * D + lane]
                                : ie[(size_t)(ck - NU) * D + lane];
        else     src = out[(size_t)ck * ROWF + (size_t)hop * D + lane];
        acc += __int_as_float(kp.y) * src;
    }

    // fused message dropout on flat index w*64+lane
    const float P_KEEP = (float)(1.0 - 0.1);
    const float INVM   = (float)(1.0 / (1.0 - 0.1));
    float um = u01(rbits(km0, km1, (uint32_t)(w * D + lane)));
    acc = (um < P_KEEP) ? acc * INVM : 0.0f;
    out[(size_t)w * ROWF + (size_t)(hop + 1) * D + lane] = acc;
}

// ------------------------- R3 mid-fallback kernels -------------------------

__global__ void init0_kernel(const float4* __restrict__ ue,
                             const float4* __restrict__ ie,
                             float4* __restrict__ out) {
    int gid = blockIdx.x * blockDim.x + threadIdx.x;
    if (gid >= NT * 16) return;
    int n = gid >> 4, q = gid & 15;
    float4 v = (n < NU) ? ue[n * 16 + q] : ie[(n - NU) * 16 + q];
    out[(size_t)n * 64 + q] = v;
}

__global__ void prep_hop_kernel(const int2* __restrict__ epair,
                                float* __restrict__ vcsr,
                                uint32_t ke0, uint32_t ke1) {
    int p = blockIdx.x * blockDim.x + threadIdx.x;
    if (p >= NNZ) return;
    int2 ev = epair[p];
    float u = u01(rbits(ke0, ke1, (uint32_t)ev.x));
    vcsr[p] = (u >= 0.5f) ? __int_as_float(ev.y) * 2.0f : 0.0f;
}

__global__ void spmm_csr_kernel(const int* __restrict__ rp,
                                const int* __restrict__ ecol,
                                const float* __restrict__ vcsr,
                                float* __restrict__ out, int hop,
                                uint32_t km0, uint32_t km1) {
    int w    = (blockIdx.x * blockDim.x + threadIdx.x) >> 6;
    int lane = threadIdx.x & 63;
    if (w >= NT) return;
    int s = rp[w], epos = rp[w + 1];
    int len = epos - s;
    float vl = 0.0f; int cl = 0;
    if (lane < len) { vl = vcsr[s + lane]; cl = ecol[s + lane]; }
    float acc = 0.0f;
    int m = (len < 64) ? len : 64;
    for (int j = 0; j < m; ++j) {
        float ve = __shfl(vl, j, 64);
        if (ve != 0.0f) {
            int c = __shfl(cl, j, 64);
            acc += ve * out[(size_t)c * ROWF + hop * D + lane];
        }
    }
    for (int j = s + 64; j < epos; ++j) {
        float ve = vcsr[j];
        if (ve == 0.0f) continue;
        acc += ve * out[(size_t)ecol[j] * ROWF + hop * D + lane];
    }
    const float P_KEEP = (float)(1.0 - 0.1);
    const float INVM   = (float)(1.0 / (1.0 - 0.1));
    float um = u01(rbits(km0, km1, (uint32_t)(w * D + lane)));
    acc = (um < P_KEEP) ? acc * INVM : 0.0f;
    out[(size_t)w * ROWF + (hop + 1) * D + lane] = acc;
}

// ------------------------- R1 small-ws fallback -------------------------

__global__ void init_kernel(const float4* __restrict__ ue,
                            const float4* __restrict__ ie,
                            float4* __restrict__ out) {
    int gid = blockIdx.x * blockDim.x + threadIdx.x;
    if (gid >= NT * 16) return;
    int n = gid >> 4, q = gid & 15;
    float4 v = (n < NU) ? ue[n * 16 + q] : ie[(n - NU) * 16 + q];
    float4 z = make_float4(0.f, 0.f, 0.f, 0.f);
    float4* row = out + (size_t)n * 64;
    row[q]      = v;
    row[16 + q] = z;
    row[32 + q] = z;
    row[48 + q] = z;
}

__global__ void spmm_inline_kernel(const float* __restrict__ vals,
                                   const int* __restrict__ rows,
                                   const int* __restrict__ cols,
                                   float* __restrict__ out, int hop,
                                   uint32_t ke0, uint32_t ke1) {
    int wid  = (blockIdx.x * blockDim.x + threadIdx.x) >> 6;
    int lane = threadIdx.x & 63;
    if (wid >= NNZ) return;
    float u = u01(rbits(ke0, ke1, (uint32_t)wid));
    if (u < 0.5f) return;
    float ve = vals[wid] * 2.0f;
    int r = rows[wid], c = cols[wid];
    float x = out[c * ROWF + hop * D + lane];
    unsafeAtomicAdd(&out[r * ROWF + (hop + 1) * D + lane], ve * x);
}

__global__ void mess_drop_kernel(float* __restrict__ out, int hop,
                                 uint32_t km0, uint32_t km1) {
    int j = blockIdx.x * blockDim.x + threadIdx.x;
    if (j >= NT * D) return;
    float u = u01(rbits(km0, km1, (uint32_t)j));
    int n = j >> 6, d = j & 63;
    int idx = n * ROWF + (hop + 1) * D + d;
    const float P_KEEP = (float)(1.0 - 0.1);
    const float INVM   = (float)(1.0 / (1.0 - 0.1));
    float a = out[idx];
    out[idx] = (u < P_KEEP) ? a * INVM : 0.0f;
}

// ------------------------- launch -------------------------

extern "C" void kernel_launch(void* const* d_in, const int* in_sizes, int n_in,
                              void* d_out, int out_size, void* d_ws, size_t ws_size,
                              hipStream_t stream) {
    const float* ue   = (const float*)d_in[0];
    const float* ie   = (const float*)d_in[1];
    const float* vals = (const float*)d_in[2];
    const int*   rows = (const int*)d_in[3];
    const int*   cols = (const int*)d_in[4];
    float* out = (float*)d_out;

    // ws layout
    const size_t off_rp    = 0;                                   // (NT+1) ints
    const size_t off_cur   = 1200016;                             // NT ints
    const size_t off_ecol  = 2400016;                             // NNZ ints
    const size_t off_epair = 7200016;                             // NNZ int2 {eid,val}
    const size_t off_vcsr  = 16800016;                            // [mid path] NNZ floats
    const size_t off_kpair = 16800016;                            // [fast path] NNZ int2 {col,val}
    const size_t off_kinfo = 26400016;                            // [fast path] NT int2 {start,len}
    const size_t need_fast = off_kinfo + (size_t)NT * 8;          // 28,800,016
    const size_t need_mid  = off_vcsr + (size_t)NNZ * 4;          // 21,600,016

    uint32_t kf0, kf1;
    uint32_t ke0[NHOPS], ke1[NHOPS], km0[NHOPS], km1[NHOPS];
    for (int h = 0; h < NHOPS; ++h) {
        tf2x32(0u, 42u, 0u, (uint32_t)h, kf0, kf1);
        tf2x32(kf0, kf1, 0u, 0u, ke0[h], ke1[h]);
        tf2x32(kf0, kf1, 0u, 1u, km0[h], km1[h]);
    }

    if (ws_size >= need_mid) {
        int*   rp    = (int*)((char*)d_ws + off_rp);
        int*   cur   = (int*)((char*)d_ws + off_cur);
        int*   ecol  = (int*)((char*)d_ws + off_ecol);
        int2*  epair = (int2*)((char*)d_ws + off_epair);
        int*   partials = cur;   // 294 ints during scan; re-zeroed before scatter

        const int n = NT + 1;
        const int nscan = (n + SCAN_BLK - 1) / SCAN_BLK;   // 294

        // CSR build (once per call, deterministic)
        zero_kernel<<<(n + 255) / 256, 256, 0, stream>>>(rp, n);
        hist_kernel<<<(NNZ + 255) / 256, 256, 0, stream>>>(rows, rp);
        scan_block_kernel<<<nscan, SCAN_BLK, 0, stream>>>(rp, partials, n);
        scan_partials_kernel<<<1, 512, 0, stream>>>(partials, nscan);
        add_offsets_kernel<<<nscan, SCAN_BLK, 0, stream>>>(rp, partials, n);
        zero_kernel<<<(NT + 255) / 256, 256, 0, stream>>>(cur, NT);
        scatter_kernel<<<(NNZ + 255) / 256, 256, 0, stream>>>(rows, cols, vals, rp, cur,
                                                              ecol, epair);

        if (ws_size >= need_fast) {
            int2* kpair = (int2*)((char*)d_ws + off_kpair);
            int2* kinfo = (int2*)((char*)d_ws + off_kinfo);
            for (int h = 0; h < NHOPS; ++h) {
                prep2_kernel<<<(NT + 255) / 256, 256, 0, stream>>>(
                    rp, ecol, epair, kpair, kinfo, ke0[h], ke1[h]);
                if (h == 0) {
                    spmm2_kernel<1><<<(NT + 3) / 4, 256, 0, stream>>>(
                        kinfo, kpair, ue, ie, out, h, km0[h], km1[h]);
                } else {
                    spmm2_kernel<0><<<(NT + 3) / 4, 256, 0, stream>>>(
                        kinfo, kpair, ue, ie, out, h, km0[h], km1[h]);
                }
            }
        } else {
            float* vcsr = (float*)((char*)d_ws + off_vcsr);
            init0_kernel<<<(NT * 16 + 255) / 256, 256, 0, stream>>>(
                (const float4*)ue, (const float4*)ie, (float4*)out);
            for (int h = 0; h < NHOPS; ++h) {
                prep_hop_kernel<<<(NNZ + 255) / 256, 256, 0, stream>>>(epair, vcsr,
                                                                       ke0[h], ke1[h]);
                spmm_csr_kernel<<<(NT + 3) / 4, 256, 0, stream>>>(
                    rp, ecol, vcsr, out, h, km0[h], km1[h]);
            }
        }
    } else {
        init_kernel<<<(NT * 16 + 255) / 256, 256, 0, stream>>>(
            (const float4*)ue, (const float4*)ie, (float4*)out);
        for (int h = 0; h < NHOPS; ++h) {
            spmm_inline_kernel<<<(NNZ + 3) / 4, 256, 0, stream>>>(
                vals, rows, cols, out, h, ke0[h], ke1[h]);
            mess_drop_kernel<<<(NT * D + 255) / 256, 256, 0, stream>>>(out, h, km0[h], km1[h]);
        }
    }
}

// Round 5
// 429.941 us; speedup vs baseline: 1.9676x; 1.1427x over previous
//
#include <hip/hip_runtime.h>
#include <stdint.h>

#define NU 100000
#define NI 200000
#define NT 300000          // NU + NI
#define D 64
#define NNZ 1200000
#define NHOPS 3
#define SL 4               // slices per row = NHOPS+1
#define ROWF (SL * D)      // 256 floats per output row
#define SCAN_BLK 1024
#define KSLOTS 8           // padded kept-edge slots per row (fast3 path)

__host__ __device__ __forceinline__ uint32_t rotl32(uint32_t x, int r) {
    return (x << r) | (x >> (32 - r));
}

// Threefry-2x32, 20 rounds — matches jax._src.prng.threefry2x32
__host__ __device__ inline void tf2x32(uint32_t k0, uint32_t k1,
                                       uint32_t x0, uint32_t x1,
                                       uint32_t& o0, uint32_t& o1) {
    uint32_t ks0 = k0, ks1 = k1, ks2 = k0 ^ k1 ^ 0x1BD11BDAu;
    x0 += ks0; x1 += ks1;
#define RND(r) { x0 += x1; x1 = rotl32(x1, r); x1 ^= x0; }
    RND(13) RND(15) RND(26) RND(6)
    x0 += ks1; x1 += ks2 + 1u;
    RND(17) RND(29) RND(16) RND(24)
    x0 += ks2; x1 += ks0 + 2u;
    RND(13) RND(15) RND(26) RND(6)
    x0 += ks0; x1 += ks1 + 3u;
    RND(17) RND(29) RND(16) RND(24)
    x0 += ks1; x1 += ks2 + 4u;
    RND(13) RND(15) RND(26) RND(6)
    o0 = x0 + ks2; o1 = x1 + ks0 + 5u;
#undef RND
}

__device__ __forceinline__ uint32_t rbits(uint32_t k0, uint32_t k1, uint32_t j) {
    uint32_t o0, o1;
    tf2x32(k0, k1, 0u, j, o0, o1);
    return o0 ^ o1;
}

__device__ __forceinline__ float u01(uint32_t bits) {
    return __uint_as_float((bits >> 9) | 0x3f800000u) - 1.0f;
}

// ------------------------- shared CSR-build kernels -------------------------

__global__ void zero_kernel(int* __restrict__ p, int n) {
    int i = blockIdx.x * blockDim.x + threadIdx.x;
    if (i < n) p[i] = 0;
}

__global__ void hist_kernel(const int* __restrict__ rows, int* __restrict__ rp) {
    int e = blockIdx.x * blockDim.x + threadIdx.x;
    if (e < NNZ) atomicAdd(&rp[rows[e] + 1], 1);
}

__global__ void scan_block_kernel(int* __restrict__ rp, int* __restrict__ partials, int n) {
    __shared__ int wsum[16];
    int tid = threadIdx.x, idx = blockIdx.x * SCAN_BLK + tid;
    int v = (idx < n) ? rp[idx] : 0;
    int lane = tid & 63, wv = tid >> 6;
    for (int o = 1; o < 64; o <<= 1) { int t = __shfl_up(v, o, 64); if (lane >= o) v += t; }
    if (lane == 63) wsum[wv] = v;
    __syncthreads();
    if (wv == 0) {
        int s = (lane < 16) ? wsum[lane] : 0;
        for (int o = 1; o < 16; o <<= 1) { int t = __shfl_up(s, o, 64); if (lane >= o) s += t; }
        if (lane < 16) wsum[lane] = s;
    }
    __syncthreads();
    int off = (wv > 0) ? wsum[wv - 1] : 0;
    v += off;
    if (idx < n) rp[idx] = v;
    if (tid == SCAN_BLK - 1) partials[blockIdx.x] = wsum[15];
}

__global__ void scan_partials_kernel(int* __restrict__ partials, int nb) {
    __shared__ int wsum[8];
    int tid = threadIdx.x;
    int v = (tid < nb) ? partials[tid] : 0;
    int own = v;
    int lane = tid & 63, wv = tid >> 6;
    for (int o = 1; o < 64; o <<= 1) { int t = __shfl_up(v, o, 64); if (lane >= o) v += t; }
    if (lane == 63) wsum[wv] = v;
    __syncthreads();
    if (wv == 0) {
        int s = (lane < 8) ? wsum[lane] : 0;
        for (int o = 1; o < 8; o <<= 1) { int t = __shfl_up(s, o, 64); if (lane >= o) s += t; }
        if (lane < 8) wsum[lane] = s;
    }
    __syncthreads();
    int off = (wv > 0) ? wsum[wv - 1] : 0;
    if (tid < nb) partials[tid] = v + off - own;
}

__global__ void add_offsets_kernel(int* __restrict__ rp, const int* __restrict__ partials, int n) {
    int idx = blockIdx.x * SCAN_BLK + threadIdx.x;
    if (idx < n && blockIdx.x > 0) rp[idx] += partials[blockIdx.x];
}

__global__ void scatter_kernel(const int* __restrict__ rows, const int* __restrict__ cols,
                               const float* __restrict__ vals,
                               const int* __restrict__ rp, int* __restrict__ cur,
                               int* __restrict__ ecol, int2* __restrict__ epair) {
    int e = blockIdx.x * blockDim.x + threadIdx.x;
    if (e >= NNZ) return;
    int r = rows[e];
    int pos = rp[r] + atomicAdd(&cur[r], 1);
    ecol[pos]  = cols[e];
    epair[pos] = make_int2(e, __float_as_int(vals[e]));
}

// ------------------------- fast3 path -------------------------

// thread per row: kept edges into padded slots kslot[r*8+k] = {col, val*2};
// zero-fill unused slots; kcnt[r] = full kept count (may exceed 8)
__global__ void prep3_kernel(const int* __restrict__ rp,
                             const int* __restrict__ ecol,
                             const int2* __restrict__ epair,
                             int2* __restrict__ kslot,
                             int* __restrict__ kcnt,
                             uint32_t ke0, uint32_t ke1) {
    int r = blockIdx.x * blockDim.x + threadIdx.x;
    if (r >= NT) return;
    int s = rp[r], e = rp[r + 1];
    int cnt = 0;
    for (int j = s; j < e; ++j) {
        int2 ev = epair[j];
        float u = u01(rbits(ke0, ke1, (uint32_t)ev.x));
        if (u >= 0.5f) {
            if (cnt < KSLOTS) {
                float v2 = __int_as_float(ev.y) * 2.0f;
                kslot[(size_t)r * KSLOTS + cnt] = make_int2(ecol[j], __float_as_int(v2));
            }
            ++cnt;
        }
    }
    for (int k = (cnt < KSLOTS ? cnt : KSLOTS); k < KSLOTS; ++k)
        kslot[(size_t)r * KSLOTS + k] = make_int2(0, 0);
    kcnt[r] = cnt;
}

// 4 rows per wave; 2-stage loads; mess-drop fused; H0 fuses slice-0 copy
template <int H0>
__global__ void spmm3_kernel(const int* __restrict__ kcnt,
                             const int2* __restrict__ kslot,
                             const int* __restrict__ rp,
                             const int* __restrict__ ecol,
                             const int2* __restrict__ epair,
                             const float* __restrict__ ue,
                             const float* __restrict__ ie,
                             float* __restrict__ out, int hop,
                             uint32_t ke0, uint32_t ke1,
                             uint32_t km0, uint32_t km1) {
    int w    = (blockIdx.x * blockDim.x + threadIdx.x) >> 6;
    int lane = threadIdx.x & 63;
    int r0   = w * 4;
    if (r0 >= NT) return;                 // NT % 4 == 0 → full quads only
    int rq = lane >> 4;                   // quarter 0..3 → row r0+rq
    int rr = r0 + rq;

    // ---- stage 1: independent loads, issued together ----
    int m = kcnt[rr];                     // quarter-uniform
    int2 kp = make_int2(0, 0);
    if (lane < 32) kp = kslot[(size_t)r0 * KSLOTS + lane];   // 256B contiguous
    float4 e04;
    if (H0) {
        // NU % 4 == 0 → the 4 rows are all-user or all-item
        const float4* s4 = (r0 < NU) ? (const float4*)(ue + (size_t)r0 * D)
                                     : (const float4*)(ie + (size_t)(r0 - NU) * D);
        e04 = s4[lane];                   // 4 rows × 64 floats, coalesced
    }

    int   cl = kp.x;
    float vl = __int_as_float(kp.y);

    int m0 = __shfl(m, 0, 64), m1 = __shfl(m, 16, 64);
    int m2 = __shfl(m, 32, 64), m3 = __shfl(m, 48, 64);
    int mxf = max(max(m0, m1), max(m2, m3));
    int mx  = (mxf < KSLOTS) ? mxf : KSLOTS;

    float acc[4] = {0.f, 0.f, 0.f, 0.f};

    // ---- stage 2: gathers, 16 in flight per iteration ----
    for (int j = 0; j < mx; j += 4) {
        float g[16], vv[16];
        #pragma unroll
        for (int r = 0; r < 4; ++r) {
            #pragma unroll
            for (int k = 0; k < 4; ++k) {
                int slot = r * KSLOTS + j + k;          // < 32
                float vrk = __shfl(vl, slot, 64);
                int   crk = __shfl(cl, slot, 64);       // wave-uniform
                float gg;
                if (H0) {
                    const float* b = (crk < NU) ? ue : ie;
                    int c2 = (crk < NU) ? crk : crk - NU;
                    gg = b[(size_t)c2 * D + lane];
                } else {
                    gg = out[(size_t)crk * ROWF + (size_t)hop * D + lane];
                }
                vv[r * 4 + k] = vrk;
                g[r * 4 + k]  = gg;
            }
        }
        #pragma unroll
        for (int t = 0; t < 16; ++t) acc[t >> 2] += vv[t] * g[t];
    }

    // ---- cold overflow: rows with kept count > KSLOTS ----
    if (mxf > KSLOTS) {
        #pragma unroll
        for (int r = 0; r < 4; ++r) {
            int mr = (r == 0) ? m0 : (r == 1) ? m1 : (r == 2) ? m2 : m3;
            if (mr > KSLOTS) {
                int s = rp[r0 + r], e = rp[r0 + r + 1];
                int cnt = 0;
                for (int j = s; j < e; ++j) {
                    int2 ev = epair[j];
                    float u = u01(rbits(ke0, ke1, (uint32_t)ev.x));
                    if (u >= 0.5f) {
                        if (cnt >= KSLOTS) {
                            int c = ecol[j];
                            float src;
                            if (H0) {
                                const float* b = (c < NU) ? ue : ie;
                                int c2 = (c < NU) ? c : c - NU;
                                src = b[(size_t)c2 * D + lane];
                            } else {
                                src = out[(size_t)c * ROWF + (size_t)hop * D + lane];
                            }
                            acc[r] += __int_as_float(ev.y) * 2.0f * src;
                        }
                        ++cnt;
                    }
                }
            }
        }
    }

    // ---- fused hop-0 slice-0 store ----
    if (H0) {
        ((float4*)out)[(size_t)(r0 + (lane >> 4)) * 64 + (lane & 15)] = e04;
    }

    // ---- fused message dropout + store ----
    const float P_KEEP = (float)(1.0 - 0.1);
    const float INVM   = (float)(1.0 / (1.0 - 0.1));
    #pragma unroll
    for (int r = 0; r < 4; ++r) {
        float um = u01(rbits(km0, km1, (uint32_t)((r0 + r) * D + lane)));
        float a  = (um < P_KEEP) ? acc[r] * INVM : 0.0f;
        out[(size_t)(r0 + r) * ROWF + (size_t)(hop + 1) * D + lane] = a;
    }
}

// ------------------------- fast2 (R4) fallback kernels -------------------------

__global__ void prep2_kernel(const int* __restrict__ rp,
                             const int* __restrict__ ecol,
                             const int2* __restrict__ epair,
                             int2* __restrict__ kpair,
                             int2* __restrict__ kinfo,
                             uint32_t ke0, uint32_t ke1) {
    int r = blockIdx.x * blockDim.x + threadIdx.x;
    if (r >= NT) return;
    int s = rp[r], e = rp[r + 1];
    int cnt = 0;
    for (int j = s; j < e; ++j) {
        int2 ev = epair[j];
        float u = u01(rbits(ke0, ke1, (uint32_t)ev.x));
        if (u >= 0.5f) {
            float v2 = __int_as_float(ev.y) * 2.0f;
            kpair[s + cnt] = make_int2(ecol[j], __float_as_int(v2));
            ++cnt;
        }
    }
    kinfo[r] = make_int2(s, cnt);
}

template <int H0>
__global__ void spmm2_kernel(const int2* __restrict__ kinfo,
                             const int2* __restrict__ kpair,
                             const float* __restrict__ ue,
                             const float* __restrict__ ie,
                             float* __restrict__ out, int hop,
                             uint32_t km0, uint32_t km1) {
    int w    = (blockIdx.x * blockDim.x + threadIdx.x) >> 6;
    int lane = threadIdx.x & 63;
    if (w >= NT) return;
    int2 si = kinfo[w];
    int s = si.x, m = si.y;
    if (H0) {
        float e0 = (w < NU) ? ue[(size_t)w * D + lane] : ie[(size_t)(w - NU) * D + lane];
        out[(size_t)w * ROWF + lane] = e0;
    }
    float vl = 0.0f; int cl = 0;
    int mm = (m < 64) ? m : 64;
    if (lane < mm) {
        int2 kp = kpair[s + lane];
        cl = kp.x; vl = __int_as_float(kp.y);
    }
    float acc = 0.0f;
    int j = 0;
    while (j < mm) {
        float vv[4]; float g[4];
        #pragma unroll
        for (int k = 0; k < 4; ++k) {
            vv[k] = __shfl(vl, j + k, 64);
            int ck = __shfl(cl, j + k, 64);
            if (H0) {
                g[k] = (ck < NU) ? ue[(size_t)ck * D + lane]
                                 : ie[(size_t)(ck - NU) * D + lane];
            } else {
                g[k] = out[(size_t)ck * ROWF + (size_t)hop * D + lane];
            }
        }
        #pragma unroll
        for (int k = 0; k < 4; ++k) acc += vv[k] * g[k];
        j += 4;
    }
    for (int j2 = s + 64; j2 < s + m; ++j2) {
        int2 kp = kpair[j2];
        int ck = kp.x;
        float src;
        if (H0) src = (ck < NU) ? ue[(size_t)ck * D + lane]
                                : ie[(size_t)(ck - NU) * D + lane];
        else     src = out[(size_t)ck * ROWF + (size_t)hop * D + lane];
        acc += __int_as_float(kp.y) * src;
    }
    const float P_KEEP = (float)(1.0 - 0.1);
    const float INVM   = (float)(1.0 / (1.0 - 0.1));
    float um = u01(rbits(km0, km1, (uint32_t)(w * D + lane)));
    acc = (um < P_KEEP) ? acc * INVM : 0.0f;
    out[(size_t)w * ROWF + (size_t)(hop + 1) * D + lane] = acc;
}

// ------------------------- mid (R2) fallback kernels -------------------------

__global__ void init0_kernel(const float4* __restrict__ ue,
                             const float4* __restrict__ ie,
                             float4* __restrict__ out) {
    int gid = blockIdx.x * blockDim.x + threadIdx.x;
    if (gid >= NT * 16) return;
    int n = gid >> 4, q = gid & 15;
    float4 v = (n < NU) ? ue[n * 16 + q] : ie[(n - NU) * 16 + q];
    out[(size_t)n * 64 + q] = v;
}

__global__ void prep_hop_kernel(const int2* __restrict__ epair,
                                float* __restrict__ vcsr,
                                uint32_t ke0, uint32_t ke1) {
    int p = blockIdx.x * blockDim.x + threadIdx.x;
    if (p >= NNZ) return;
    int2 ev = epair[p];
    float u = u01(rbits(ke0, ke1, (uint32_t)ev.x));
    vcsr[p] = (u >= 0.5f) ? __int_as_float(ev.y) * 2.0f : 0.0f;
}

__global__ void spmm_csr_kernel(const int* __restrict__ rp,
                                const int* __restrict__ ecol,
                                const float* __restrict__ vcsr,
                                float* __restrict__ out, int hop,
                                uint32_t km0, uint32_t km1) {
    int w    = (blockIdx.x * blockDim.x + threadIdx.x) >> 6;
    int lane = threadIdx.x & 63;
    if (w >= NT) return;
    int s = rp[w], epos = rp[w + 1];
    int len = epos - s;
    float vl = 0.0f; int cl = 0;
    if (lane < len) { vl = vcsr[s + lane]; cl = ecol[s + lane]; }
    float acc = 0.0f;
    int m = (len < 64) ? len : 64;
    for (int j = 0; j < m; ++j) {
        float ve = __shfl(vl, j, 64);
        if (ve != 0.0f) {
            int c = __shfl(cl, j, 64);
            acc += ve * out[(size_t)c * ROWF + hop * D + lane];
        }
    }
    for (int j = s + 64; j < epos; ++j) {
        float ve = vcsr[j];
        if (ve == 0.0f) continue;
        acc += ve * out[(size_t)ecol[j] * ROWF + hop * D + lane];
    }
    const float P_KEEP = (float)(1.0 - 0.1);
    const float INVM   = (float)(1.0 / (1.0 - 0.1));
    float um = u01(rbits(km0, km1, (uint32_t)(w * D + lane)));
    acc = (um < P_KEEP) ? acc * INVM : 0.0f;
    out[(size_t)w * ROWF + (hop + 1) * D + lane] = acc;
}

// ------------------------- R1 small-ws fallback -------------------------

__global__ void init_kernel(const float4* __restrict__ ue,
                            const float4* __restrict__ ie,
                            float4* __restrict__ out) {
    int gid = blockIdx.x * blockDim.x + threadIdx.x;
    if (gid >= NT * 16) return;
    int n = gid >> 4, q = gid & 15;
    float4 v = (n < NU) ? ue[n * 16 + q] : ie[(n - NU) * 16 + q];
    float4 z = make_float4(0.f, 0.f, 0.f, 0.f);
    float4* row = out + (size_t)n * 64;
    row[q]      = v;
    row[16 + q] = z;
    row[32 + q] = z;
    row[48 + q] = z;
}

__global__ void spmm_inline_kernel(const float* __restrict__ vals,
                                   const int* __restrict__ rows,
                                   const int* __restrict__ cols,
                                   float* __restrict__ out, int hop,
                                   uint32_t ke0, uint32_t ke1) {
    int wid  = (blockIdx.x * blockDim.x + threadIdx.x) >> 6;
    int lane = threadIdx.x & 63;
    if (wid >= NNZ) return;
    float u = u01(rbits(ke0, ke1, (uint32_t)wid));
    if (u < 0.5f) return;
    float ve = vals[wid] * 2.0f;
    int r = rows[wid], c = cols[wid];
    float x = out[c * ROWF + hop * D + lane];
    unsafeAtomicAdd(&out[r * ROWF + (hop + 1) * D + lane], ve * x);
}

__global__ void mess_drop_kernel(float* __restrict__ out, int hop,
                                 uint32_t km0, uint32_t km1) {
    int j = blockIdx.x * blockDim.x + threadIdx.x;
    if (j >= NT * D) return;
    float u = u01(rbits(km0, km1, (uint32_t)j));
    int n = j >> 6, d = j & 63;
    int idx = n * ROWF + (hop + 1) * D + d;
    const float P_KEEP = (float)(1.0 - 0.1);
    const float INVM   = (float)(1.0 / (1.0 - 0.1));
    float a = out[idx];
    out[idx] = (u < P_KEEP) ? a * INVM : 0.0f;
}

// ------------------------- launch -------------------------

extern "C" void kernel_launch(void* const* d_in, const int* in_sizes, int n_in,
                              void* d_out, int out_size, void* d_ws, size_t ws_size,
                              hipStream_t stream) {
    const float* ue   = (const float*)d_in[0];
    const float* ie   = (const float*)d_in[1];
    const float* vals = (const float*)d_in[2];
    const int*   rows = (const int*)d_in[3];
    const int*   cols = (const int*)d_in[4];
    float* out = (float*)d_out;

    // ws layout
    const size_t off_rp    = 0;                                   // (NT+1) ints
    const size_t off_cur   = 1200016;                             // NT ints (+partials)
    const size_t off_ecol  = 2400016;                             // NNZ ints
    const size_t off_epair = 7200016;                             // NNZ int2 {eid,val}
    const size_t off_vcsr  = 16800016;                            // [mid]  NNZ floats
    const size_t off_kpair = 16800016;                            // [fast2] NNZ int2
    const size_t off_kinfo = 26400016;                            // [fast2] NT int2
    const size_t off_kslot = 16800016;                            // [fast3] NT*8 int2 = 19.2MB
    const size_t off_kcnt  = 36000016;                            // [fast3] NT ints
    const size_t need_f3   = off_kcnt + (size_t)NT * 4;           // 37,200,016
    const size_t need_f2   = off_kinfo + (size_t)NT * 8;          // 28,800,016
    const size_t need_mid  = off_vcsr + (size_t)NNZ * 4;          // 21,600,016

    uint32_t kf0, kf1;
    uint32_t ke0[NHOPS], ke1[NHOPS], km0[NHOPS], km1[NHOPS];
    for (int h = 0; h < NHOPS; ++h) {
        tf2x32(0u, 42u, 0u, (uint32_t)h, kf0, kf1);
        tf2x32(kf0, kf1, 0u, 0u, ke0[h], ke1[h]);
        tf2x32(kf0, kf1, 0u, 1u, km0[h], km1[h]);
    }

    if (ws_size >= need_mid) {
        int*   rp    = (int*)((char*)d_ws + off_rp);
        int*   cur   = (int*)((char*)d_ws + off_cur);
        int*   ecol  = (int*)((char*)d_ws + off_ecol);
        int2*  epair = (int2*)((char*)d_ws + off_epair);
        int*   partials = cur;

        const int n = NT + 1;
        const int nscan = (n + SCAN_BLK - 1) / SCAN_BLK;

        zero_kernel<<<(n + 255) / 256, 256, 0, stream>>>(rp, n);
        hist_kernel<<<(NNZ + 255) / 256, 256, 0, stream>>>(rows, rp);
        scan_block_kernel<<<nscan, SCAN_BLK, 0, stream>>>(rp, partials, n);
        scan_partials_kernel<<<1, 512, 0, stream>>>(partials, nscan);
        add_offsets_kernel<<<nscan, SCAN_BLK, 0, stream>>>(rp, partials, n);
        zero_kernel<<<(NT + 255) / 256, 256, 0, stream>>>(cur, NT);
        scatter_kernel<<<(NNZ + 255) / 256, 256, 0, stream>>>(rows, cols, vals, rp, cur,
                                                              ecol, epair);

        if (ws_size >= need_f3) {
            int2* kslot = (int2*)((char*)d_ws + off_kslot);
            int*  kcnt  = (int*)((char*)d_ws + off_kcnt);
            for (int h = 0; h < NHOPS; ++h) {
                prep3_kernel<<<(NT + 255) / 256, 256, 0, stream>>>(
                    rp, ecol, epair, kslot, kcnt, ke0[h], ke1[h]);
                if (h == 0)
                    spmm3_kernel<1><<<(NT / 4 * 64 + 255) / 256, 256, 0, stream>>>(
                        kcnt, kslot, rp, ecol, epair, ue, ie, out, h,
                        ke0[h], ke1[h], km0[h], km1[h]);
                else
                    spmm3_kernel<0><<<(NT / 4 * 64 + 255) / 256, 256, 0, stream>>>(
                        kcnt, kslot, rp, ecol, epair, ue, ie, out, h,
                        ke0[h], ke1[h], km0[h], km1[h]);
            }
        } else if (ws_size >= need_f2) {
            int2* kpair = (int2*)((char*)d_ws + off_kpair);
            int2* kinfo = (int2*)((char*)d_ws + off_kinfo);
            for (int h = 0; h < NHOPS; ++h) {
                prep2_kernel<<<(NT + 255) / 256, 256, 0, stream>>>(
                    rp, ecol, epair, kpair, kinfo, ke0[h], ke1[h]);
                if (h == 0)
                    spmm2_kernel<1><<<(NT + 3) / 4, 256, 0, stream>>>(
                        kinfo, kpair, ue, ie, out, h, km0[h], km1[h]);
                else
                    spmm2_kernel<0><<<(NT + 3) / 4, 256, 0, stream>>>(
                        kinfo, kpair, ue, ie, out, h, km0[h], km1[h]);
            }
        } else {
            float* vcsr = (float*)((char*)d_ws + off_vcsr);
            init0_kernel<<<(NT * 16 + 255) / 256, 256, 0, stream>>>(
                (const float4*)ue, (const float4*)ie, (float4*)out);
            for (int h = 0; h < NHOPS; ++h) {
                prep_hop_kernel<<<(NNZ + 255) / 256, 256, 0, stream>>>(epair, vcsr,
                                                                       ke0[h], ke1[h]);
                spmm_csr_kernel<<<(NT + 3) / 4, 256, 0, stream>>>(
                    rp, ecol, vcsr, out, h, km0[h], km1[h]);
            }
        }
    } else {
        init_kernel<<<(NT * 16 + 255) / 256, 256, 0, stream>>>(
            (const float4*)ue, (const float4*)ie, (float4*)out);
        for (int h = 0; h < NHOPS; ++h) {
            spmm_inline_kernel<<<(NNZ + 3) / 4, 256, 0, stream>>>(
                vals, rows, cols, out, h, ke0[h], ke1[h]);
            mess_drop_kernel<<<(NT * D + 255) / 256, 256, 0, stream>>>(out, h, km0[h], km1[h]);
        }
    }
}

// Round 6
// 342.361 us; speedup vs baseline: 2.4709x; 1.2558x over previous
//
#include <hip/hip_runtime.h>
#include <stdint.h>

#define NU 100000
#define NI 200000
#define NT 300000          // NU + NI
#define D 64
#define NNZ 1200000
#define NHOPS 3
#define SL 4               // slices per row = NHOPS+1
#define ROWF (SL * D)      // 256 floats per output row
#define KS 8               // padded kept-edge slots per row
#define OVF_CAP 16384      // overflow entries (rows with >KS kept edges)

__host__ __device__ __forceinline__ uint32_t rotl32(uint32_t x, int r) {
    return (x << r) | (x >> (32 - r));
}

// Threefry-2x32, 20 rounds — matches jax._src.prng.threefry2x32
__host__ __device__ inline void tf2x32(uint32_t k0, uint32_t k1,
                                       uint32_t x0, uint32_t x1,
                                       uint32_t& o0, uint32_t& o1) {
    uint32_t ks0 = k0, ks1 = k1, ks2 = k0 ^ k1 ^ 0x1BD11BDAu;
    x0 += ks0; x1 += ks1;
#define RND(r) { x0 += x1; x1 = rotl32(x1, r); x1 ^= x0; }
    RND(13) RND(15) RND(26) RND(6)
    x0 += ks1; x1 += ks2 + 1u;
    RND(17) RND(29) RND(16) RND(24)
    x0 += ks2; x1 += ks0 + 2u;
    RND(13) RND(15) RND(26) RND(6)
    x0 += ks0; x1 += ks1 + 3u;
    RND(17) RND(29) RND(16) RND(24)
    x0 += ks1; x1 += ks2 + 4u;
    RND(13) RND(15) RND(26) RND(6)
    o0 = x0 + ks2; o1 = x1 + ks0 + 5u;
#undef RND
}

__device__ __forceinline__ uint32_t rbits(uint32_t k0, uint32_t k1, uint32_t j) {
    uint32_t o0, o1;
    tf2x32(k0, k1, 0u, j, o0, o1);
    return o0 ^ o1;
}

__device__ __forceinline__ float u01(uint32_t bits) {
    return __uint_as_float((bits >> 9) | 0x3f800000u) - 1.0f;
}

// ------------------------- fast path -------------------------

__global__ void zero_kernel(int* __restrict__ p, int n) {
    int i = blockIdx.x * blockDim.x + threadIdx.x;
    if (i < n) p[i] = 0;
}

// per-hop direct scatter of KEPT edges into padded slots.
// kcnt[NT] doubles as the overflow counter.
__global__ void scat_kernel(const int* __restrict__ rows,
                            const int* __restrict__ cols,
                            const float* __restrict__ vals,
                            int* __restrict__ kcnt,
                            int2* __restrict__ kslot,
                            int4* __restrict__ ovf,
                            uint32_t ke0, uint32_t ke1) {
    int e = blockIdx.x * blockDim.x + threadIdx.x;
    if (e >= NNZ) return;
    float u = u01(rbits(ke0, ke1, (uint32_t)e));
    if (u < 0.5f) return;                       // dropped edge
    int r = rows[e];
    int c = cols[e];
    float v2 = vals[e] * 2.0f;                  // 1/(1-0.5) scale, exact
    int pos = atomicAdd(&kcnt[r], 1);
    if (pos < KS) {
        kslot[(size_t)r * KS + pos] = make_int2(c, __float_as_int(v2));
    } else {
        int oi = atomicAdd(&kcnt[NT], 1);
        if (oi < OVF_CAP) ovf[oi] = make_int4(r, c, __float_as_int(v2), 0);
    }
}

// 8 rows per wave; lane = feature dim; mess-drop fused; H0 fuses slice-0 copy
template <int H0>
__global__ void spmm8_kernel(const int* __restrict__ kcnt,
                             const int2* __restrict__ kslot,
                             const int4* __restrict__ ovf,
                             const float* __restrict__ ue,
                             const float* __restrict__ ie,
                             float* __restrict__ out, int hop,
                             uint32_t km0, uint32_t km1) {
    int w    = (blockIdx.x * blockDim.x + threadIdx.x) >> 6;
    int lane = threadIdx.x & 63;
    int r0   = w * 8;
    if (r0 >= NT) return;                       // NT % 8 == 0

    // ---- stage 1: independent loads, issued together ----
    int mk = 0;
    if (lane < 8) mk = kcnt[r0 + lane];
    int2 kp = kslot[(size_t)r0 * KS + lane];    // 8 rows x 8 slots = 64 = 1/lane

    float4 e04a, e04b;
    if (H0) {
        // NU % 8 == 0 → all 8 rows on the same side of the user/item split
        const float4* s4 = (r0 < NU) ? (const float4*)(ue + (size_t)r0 * D)
                                     : (const float4*)(ie + (size_t)(r0 - NU) * D);
        e04a = s4[lane];
        e04b = s4[lane + 64];
    }

    int   cl = kp.x;
    float vl = __int_as_float(kp.y);

    int m[8];
    #pragma unroll
    for (int r = 0; r < 8; ++r) m[r] = __shfl(mk, r, 64);
    int mxf = 0;
    #pragma unroll
    for (int r = 0; r < 8; ++r) mxf = max(mxf, m[r]);
    int mx = (mxf < KS) ? mxf : KS;

    float acc[8] = {0.f, 0.f, 0.f, 0.f, 0.f, 0.f, 0.f, 0.f};

    // ---- stage 2: gathers, 8 independent per iteration ----
    for (int j = 0; j < mx; ++j) {
        float vv[8]; int cc[8];
        #pragma unroll
        for (int r = 0; r < 8; ++r) {
            int slot = r * KS + j;
            float v = __shfl(vl, slot, 64);
            int   c = __shfl(cl, slot, 64);
            bool ok = (j < m[r]);               // guards 0xAA garbage in unused slots
            vv[r] = ok ? v : 0.0f;
            cc[r] = ok ? c : 0;
        }
        float g[8];
        #pragma unroll
        for (int r = 0; r < 8; ++r) {
            if (H0) {
                const float* b = (cc[r] < NU) ? ue : ie;
                int c2 = (cc[r] < NU) ? cc[r] : cc[r] - NU;
                g[r] = b[(size_t)c2 * D + lane];
            } else {
                g[r] = out[(size_t)cc[r] * ROWF + (size_t)hop * D + lane];
            }
        }
        #pragma unroll
        for (int r = 0; r < 8; ++r) acc[r] += vv[r] * g[r];
    }

    // ---- cold overflow: rows with kept count > KS (expected ~60/hop chip-wide) ----
    if (mxf > KS) {
        int no = kcnt[NT];
        if (no > OVF_CAP) no = OVF_CAP;
        #pragma unroll
        for (int r = 0; r < 8; ++r) {           // static acc index (rule #20)
            if (m[r] > KS) {
                for (int i = 0; i < no; ++i) {
                    int4 ent = ovf[i];
                    if (ent.x == r0 + r) {
                        float src;
                        if (H0) {
                            const float* b = (ent.y < NU) ? ue : ie;
                            int c2 = (ent.y < NU) ? ent.y : ent.y - NU;
                            src = b[(size_t)c2 * D + lane];
                        } else {
                            src = out[(size_t)ent.y * ROWF + (size_t)hop * D + lane];
                        }
                        acc[r] += __int_as_float(ent.z) * src;
                    }
                }
            }
        }
    }

    // ---- fused hop-0 slice-0 copy ----
    if (H0) {
        int f0 = lane, f1 = lane + 64;
        ((float4*)out)[(size_t)(r0 + (f0 >> 4)) * 64 + (f0 & 15)] = e04a;
        ((float4*)out)[(size_t)(r0 + (f1 >> 4)) * 64 + (f1 & 15)] = e04b;
    }

    // ---- fused message dropout + store ----
    const float P_KEEP = (float)(1.0 - 0.1);
    const float INVM   = (float)(1.0 / (1.0 - 0.1));
    #pragma unroll
    for (int r = 0; r < 8; ++r) {
        float um = u01(rbits(km0, km1, (uint32_t)((r0 + r) * D + lane)));
        float a  = (um < P_KEEP) ? acc[r] * INVM : 0.0f;
        out[(size_t)(r0 + r) * ROWF + (size_t)(hop + 1) * D + lane] = a;
    }
}

// ------------------------- R1 small-ws fallback -------------------------

__global__ void init_kernel(const float4* __restrict__ ue,
                            const float4* __restrict__ ie,
                            float4* __restrict__ out) {
    int gid = blockIdx.x * blockDim.x + threadIdx.x;
    if (gid >= NT * 16) return;
    int n = gid >> 4, q = gid & 15;
    float4 v = (n < NU) ? ue[n * 16 + q] : ie[(n - NU) * 16 + q];
    float4 z = make_float4(0.f, 0.f, 0.f, 0.f);
    float4* row = out + (size_t)n * 64;
    row[q]      = v;
    row[16 + q] = z;
    row[32 + q] = z;
    row[48 + q] = z;
}

__global__ void spmm_inline_kernel(const float* __restrict__ vals,
                                   const int* __restrict__ rows,
                                   const int* __restrict__ cols,
                                   float* __restrict__ out, int hop,
                                   uint32_t ke0, uint32_t ke1) {
    int wid  = (blockIdx.x * blockDim.x + threadIdx.x) >> 6;
    int lane = threadIdx.x & 63;
    if (wid >= NNZ) return;
    float u = u01(rbits(ke0, ke1, (uint32_t)wid));
    if (u < 0.5f) return;
    float ve = vals[wid] * 2.0f;
    int r = rows[wid], c = cols[wid];
    float x = out[c * ROWF + hop * D + lane];
    unsafeAtomicAdd(&out[r * ROWF + (hop + 1) * D + lane], ve * x);
}

__global__ void mess_drop_kernel(float* __restrict__ out, int hop,
                                 uint32_t km0, uint32_t km1) {
    int j = blockIdx.x * blockDim.x + threadIdx.x;
    if (j >= NT * D) return;
    float u = u01(rbits(km0, km1, (uint32_t)j));
    int n = j >> 6, d = j & 63;
    int idx = n * ROWF + (hop + 1) * D + d;
    const float P_KEEP = (float)(1.0 - 0.1);
    const float INVM   = (float)(1.0 / (1.0 - 0.1));
    float a = out[idx];
    out[idx] = (u < P_KEEP) ? a * INVM : 0.0f;
}

// ------------------------- launch -------------------------

extern "C" void kernel_launch(void* const* d_in, const int* in_sizes, int n_in,
                              void* d_out, int out_size, void* d_ws, size_t ws_size,
                              hipStream_t stream) {
    const float* ue   = (const float*)d_in[0];
    const float* ie   = (const float*)d_in[1];
    const float* vals = (const float*)d_in[2];
    const int*   rows = (const int*)d_in[3];
    const int*   cols = (const int*)d_in[4];
    float* out = (float*)d_out;

    // ws layout (fast path): kcnt (NT+1 ints) | kslot (NT*KS int2) | ovf (int4)
    const size_t off_kcnt  = 0;
    const size_t off_kslot = 1200016;                              // 16B aligned
    const size_t off_ovf   = off_kslot + (size_t)NT * KS * 8;      // 20,400,016
    const size_t need      = off_ovf + (size_t)OVF_CAP * 16;       // 20,662,160

    uint32_t kf0, kf1;
    uint32_t ke0[NHOPS], ke1[NHOPS], km0[NHOPS], km1[NHOPS];
    for (int h = 0; h < NHOPS; ++h) {
        tf2x32(0u, 42u, 0u, (uint32_t)h, kf0, kf1);
        tf2x32(kf0, kf1, 0u, 0u, ke0[h], ke1[h]);
        tf2x32(kf0, kf1, 0u, 1u, km0[h], km1[h]);
    }

    if (ws_size >= need) {
        int*  kcnt  = (int*)((char*)d_ws + off_kcnt);
        int2* kslot = (int2*)((char*)d_ws + off_kslot);
        int4* ovf   = (int4*)((char*)d_ws + off_ovf);

        for (int h = 0; h < NHOPS; ++h) {
            zero_kernel<<<(NT + 1 + 255) / 256, 256, 0, stream>>>(kcnt, NT + 1);
            scat_kernel<<<(NNZ + 255) / 256, 256, 0, stream>>>(
                rows, cols, vals, kcnt, kslot, ovf, ke0[h], ke1[h]);
            if (h == 0)
                spmm8_kernel<1><<<(NT / 8 * 64 + 255) / 256, 256, 0, stream>>>(
                    kcnt, kslot, ovf, ue, ie, out, h, km0[h], km1[h]);
            else
                spmm8_kernel<0><<<(NT / 8 * 64 + 255) / 256, 256, 0, stream>>>(
                    kcnt, kslot, ovf, ue, ie, out, h, km0[h], km1[h]);
        }
    } else {
        init_kernel<<<(NT * 16 + 255) / 256, 256, 0, stream>>>(
            (const float4*)ue, (const float4*)ie, (float4*)out);
        for (int h = 0; h < NHOPS; ++h) {
            spmm_inline_kernel<<<(NNZ + 3) / 4, 256, 0, stream>>>(
                vals, rows, cols, out, h, ke0[h], ke1[h]);
            mess_drop_kernel<<<(NT * D + 255) / 256, 256, 0, stream>>>(out, h, km0[h], km1[h]);
        }
    }
}